// Round 12
// baseline (293.959 us; speedup 1.0000x reference)
//
#include <hip/hip_runtime.h>
#include <math.h>

#define DIM   2048
#define NH    16
#define HD    128
#define SEQQ  1024
#define BSZ   2
#define AL    10
#define MAXF  10
#define KVROWS (SEQQ + AL)   /* legacy per-batch K/V rows (fallback path) */
#define BK    32
#define VTP   2080           /* V^T pitch: 2048 tok + 10 adapter + 22 zero pad
                                (adapter MFMA reads tokens up to 2079) */

typedef unsigned short ushort_t;
typedef __bf16   bf16x8 __attribute__((ext_vector_type(8)));
typedef float    f32x4  __attribute__((ext_vector_type(4)));
typedef ushort_t us8    __attribute__((ext_vector_type(8)));

#define AS1 __attribute__((address_space(1)))
#define AS3 __attribute__((address_space(3)))

__device__ __forceinline__ float b2f(ushort_t u) {
    return __uint_as_float(((unsigned int)u) << 16);
}
__device__ __forceinline__ ushort_t f2b(float f) {
    unsigned int u = __float_as_uint(f);
    u += 0x7fffu + ((u >> 16) & 1u);   // round-to-nearest-even
    return (ushort_t)(u >> 16);
}
// non-finite check immune to fast-math: exponent all-ones => Inf or NaN
__device__ __forceinline__ float scrub(float v, float canary) {
    return ((__float_as_uint(v) & 0x7f800000u) == 0x7f800000u) ? canary : v;
}
// 8 consecutive fp32 -> bf16x8 fragment (RNE)
__device__ __forceinline__ bf16x8 cvt8(const float* p) {
    float4 a = *(const float4*)p;
    float4 b = *(const float4*)(p + 4);
    us8 u;
    u[0] = f2b(a.x); u[1] = f2b(a.y); u[2] = f2b(a.z); u[3] = f2b(a.w);
    u[4] = f2b(b.x); u[5] = f2b(b.y); u[6] = f2b(b.z); u[7] = f2b(b.w);
    return *(bf16x8*)&u;
}

// ---------------------------------------------------------------------------
// fp32 -> bf16 bulk convert, 8 elems/thread, 5 arrays (blockIdx.y selects).
// Each array exactly 4,194,304 elems -> grid (2048, 5), no bounds check.
// ---------------------------------------------------------------------------
__global__ __launch_bounds__(256) void cvt5(
    const float* __restrict__ s0, const float* __restrict__ s1,
    const float* __restrict__ s2, const float* __restrict__ s3,
    const float* __restrict__ s4,
    ushort_t* __restrict__ d0, ushort_t* __restrict__ d1,
    ushort_t* __restrict__ d2, ushort_t* __restrict__ d3,
    ushort_t* __restrict__ d4)
{
    const int y = blockIdx.y;
    const float* s = (y == 0) ? s0 : (y == 1) ? s1 : (y == 2) ? s2 : (y == 3) ? s3 : s4;
    ushort_t*    d = (y == 0) ? d0 : (y == 1) ? d1 : (y == 2) ? d2 : (y == 3) ? d3 : d4;
    size_t i = (size_t)blockIdx.x * 256 + threadIdx.x;   // group-of-8 index
    float4 a = ((const float4*)s)[2 * i];
    float4 b = ((const float4*)s)[2 * i + 1];
    us8 u;
    u[0] = f2b(a.x); u[1] = f2b(a.y); u[2] = f2b(a.z); u[3] = f2b(a.w);
    u[4] = f2b(b.x); u[5] = f2b(b.y); u[6] = f2b(b.z); u[7] = f2b(b.w);
    *(us8*)(d + i * 8) = u;
}

// ---------------------------------------------------------------------------
// Adapter projection. z=0: K rows (token-major, rows 2048..2057 of Kb).
// z=1: V -> V^T global [dim][VTP], tokens 2048..2057, AND zeroes pad tokens
// 2058..2079 (required: attn reads them as MFMA operands; ws is poisoned).
// 512 blocks; block stages adapter in LDS bf16, wave dots one weight row.
// ---------------------------------------------------------------------------
__global__ __launch_bounds__(256) void adapter_gemm(
    const float* __restrict__ adp,
    const ushort_t* __restrict__ Wkb, const ushort_t* __restrict__ Wvb,
    ushort_t* __restrict__ Ko, ushort_t* __restrict__ VtO,
    float canary)
{
    __shared__ ushort_t Al[AL * DIM];   // 40 KB

    const int t = threadIdx.x;
    #pragma unroll
    for (int p = 0; p < 10; ++p) {      // 2560 groups of 8 / 256 threads
        int i = p * 256 + t;
        const float* sp = adp + i * 8;
        float4 a = *(const float4*)sp;
        float4 b = *(const float4*)(sp + 4);
        us8 u;
        u[0] = f2b(a.x); u[1] = f2b(a.y); u[2] = f2b(a.z); u[3] = f2b(a.w);
        u[4] = f2b(b.x); u[5] = f2b(b.y); u[6] = f2b(b.z); u[7] = f2b(b.w);
        *(us8*)(Al + i * 8) = u;
    }
    __syncthreads();

    const int z = blockIdx.x >> 8;
    const ushort_t* W = z ? Wvb : Wkb;
    const int nbase = (blockIdx.x & 255) * 8;
    const int w = t >> 6, lane = t & 63;

    #pragma unroll
    for (int nn = 0; nn < 2; ++nn) {
        const int n = nbase + w * 2 + nn;
        const ushort_t* wr = W + (size_t)n * DIM;
        float acc[AL] = {};
        #pragma unroll
        for (int c = 0; c < 4; ++c) {
            const int k = c * 512 + lane * 8;
            us8 b8 = *(const us8*)(wr + k);
            float bf[8];
            #pragma unroll
            for (int j = 0; j < 8; ++j) bf[j] = b2f(b8[j]);
            #pragma unroll
            for (int m = 0; m < AL; ++m) {
                us8 a8 = *(const us8*)(Al + m * DIM + k);
                #pragma unroll
                for (int j = 0; j < 8; ++j)
                    acc[m] = fmaf(b2f(a8[j]), bf[j], acc[m]);
            }
        }
        #pragma unroll
        for (int m = 0; m < AL; ++m) {
            float v = acc[m];
            v += __shfl_xor(v, 1);  v += __shfl_xor(v, 2);
            v += __shfl_xor(v, 4);  v += __shfl_xor(v, 8);
            v += __shfl_xor(v, 16); v += __shfl_xor(v, 32);
            if (lane == 0) {
                ushort_t ov = f2b(scrub(v, canary));
                if (z) VtO[(size_t)n * VTP + 2048 + m] = ov;
                else   Ko[(size_t)m * DIM + n] = ov;
            }
        }
        if (z && lane < 22) VtO[(size_t)n * VTP + 2058 + lane] = 0;  // zero pad
    }
}

// ---------------------------------------------------------------------------
// QKV GEMM v2: C[M,2048] = A * B^T, fp32 acc. 128x128 tile, BK=64 (r12):
// halves barrier count (64 -> 32 drains) and XOR-swizzles LDS both sides
// (rule 21: linear dest + pre-swizzled global source + swizzled reads) so
// fragment reads hit all 32 banks (old [128][32] layout: 6.29M conflict
// cycles/dispatch). LDS 32 KB -> still 3 blocks/CU; __launch_bounds__(256,4)
// caps VGPR <=128 to preserve 16-wave/CU capacity (m132 lesson: occupancy
// loss, not BK, caused the BK=128 regression).
// Grid (16,16,NZ), (256*NZ)%8==0 (bijective XCD swizzle).
// MODE 0: z=0 Q (RoPE+qscale fused), z=1 K (RoPE fused), z=2 V^T [dim][VTP].
// RoPE: cols pair (even,odd) = lanes (ln, ln^1) -> one shfl_xor(v,1).
// ---------------------------------------------------------------------------
template<int MODE>
__global__ __launch_bounds__(256, 4) void gemm_bt(
    const ushort_t* __restrict__ A,
    const ushort_t* __restrict__ B0, const ushort_t* __restrict__ B1, const ushort_t* __restrict__ B2,
    void* __restrict__ C0, void* __restrict__ C1, void* __restrict__ C2,
    const float* __restrict__ fc, const float* __restrict__ fs,
    float qscale, float canary)
{
    __shared__ ushort_t As[128 * 64];   // 16 KB
    __shared__ ushort_t Bs[128 * 64];   // 16 KB

    // bijective XCD swizzle: nwg = 256*gridDim.z, chunk = nwg/8 per XCD
    const int lid  = blockIdx.x + (blockIdx.y << 4) + (blockIdx.z << 8);
    const int cpx  = (int)(gridDim.z << 5);          // (256*z)/8
    const int wgid = (lid & 7) * cpx + (lid >> 3);
    const int z    = wgid >> 8;
    const int rem  = wgid & 255;
    const int m0   = (rem >> 4) << 7;
    const int n0   = (rem & 15) << 7;

    const ushort_t* B = (z == 0) ? B0 : (z == 1) ? B1 : B2;
    void*           C = (z == 0) ? C0 : (z == 1) ? C1 : C2;

    const int t = threadIdx.x;
    const int w = t >> 6, lane = t & 63;
    const int ln = lane & 15, qd = lane >> 4;
    const int wrow = (w >> 1) * 64, wcol = (w & 1) * 64;

    // staging: 1024 16B-chunks per array; chunk i = t+256p: row = i>>3,
    // source 16B-slot = (i&7)^(row&7) (inverse swizzle), LDS dest linear.
    const ushort_t* Agp[4]; const ushort_t* Bgp[4];
    ushort_t* Alp[4]; ushort_t* Blp[4];
    #pragma unroll
    for (int p = 0; p < 4; ++p) {
        int i = t + 256 * p;
        int row = i >> 3, sl = (i & 7) ^ (row & 7);
        Agp[p] = A + (size_t)(m0 + row) * DIM + sl * 8;
        Bgp[p] = B + (size_t)(n0 + row) * DIM + sl * 8;
        Alp[p] = As + (size_t)i * 8;
        Blp[p] = Bs + (size_t)i * 8;
    }

    f32x4 acc[4][4] = {};

    for (int k0 = 0; k0 < DIM; k0 += 64) {
        if (k0) __syncthreads();
        #pragma unroll
        for (int p = 0; p < 4; ++p) {
            __builtin_amdgcn_global_load_lds((const AS1 void*)(Agp[p] + k0), (AS3 void*)Alp[p], 16, 0, 0);
            __builtin_amdgcn_global_load_lds((const AS1 void*)(Bgp[p] + k0), (AS3 void*)Blp[p], 16, 0, 0);
        }
        __syncthreads();

        #pragma unroll
        for (int kk = 0; kk < 2; ++kk) {
            bf16x8 af[4], bfr[4];
            #pragma unroll
            for (int i = 0; i < 4; ++i) {
                const int ar = wrow + i * 16 + ln;
                const int br = wcol + i * 16 + ln;
                af[i]  = *(const bf16x8*)(As + (size_t)ar * 64 + (((kk << 2) + qd) ^ (ar & 7)) * 8);
                bfr[i] = *(const bf16x8*)(Bs + (size_t)br * 64 + (((kk << 2) + qd) ^ (br & 7)) * 8);
            }
            #pragma unroll
            for (int i = 0; i < 4; ++i)
                #pragma unroll
                for (int j = 0; j < 4; ++j)
                    acc[i][j] = __builtin_amdgcn_mfma_f32_16x16x32_bf16(af[i], bfr[j], acc[i][j], 0, 0, 0);
        }
    }

    const float rsc = (MODE == 0 && z == 0) ? qscale : 1.0f;

    #pragma unroll
    for (int i = 0; i < 4; ++i) {
        #pragma unroll
        for (int j = 0; j < 4; ++j) {
            const int gn = n0 + wcol + j * 16 + ln;
            const int gm0 = m0 + wrow + i * 16 + qd * 4;
            if (MODE == 0 && z == 2) {
                // V^T store: 4 consecutive tokens (r) in one ushort4
                ushort4 ov;
                ov.x = f2b(scrub(acc[i][j][0], canary));
                ov.y = f2b(scrub(acc[i][j][1], canary));
                ov.z = f2b(scrub(acc[i][j][2], canary));
                ov.w = f2b(scrub(acc[i][j][3], canary));
                *(ushort4*)((ushort_t*)C + (size_t)gn * VTP + gm0) = ov;
            } else if (MODE == 0) {
                // z=0/1: fused RoPE (+qscale for Q). Pair partner in lane^1.
                const int fidx = (gn & 127) >> 1;
                #pragma unroll
                for (int r = 0; r < 4; ++r) {
                    const int gm = gm0 + r;
                    float v = scrub(acc[i][j][r], canary);
                    float po = __shfl_xor(v, 1);
                    const int fo = ((gm & 1023) << 6) + fidx;
                    float c = fc[fo], s = fs[fo];
                    float ov = (ln & 1) ? (po * s + v * c) : (v * c - po * s);
                    ((ushort_t*)C)[(size_t)gm * DIM + gn] = f2b(ov * rsc);
                }
            } else {
                #pragma unroll
                for (int r = 0; r < 4; ++r) {
                    float v = scrub(acc[i][j][r], canary);
                    ((float*)C)[(size_t)(gm0 + r) * DIM + gn] = v;
                }
            }
        }
    }
}

// ---------------------------------------------------------------------------
// WO projection (r8 best-measured config): C[2048,2048] fp32 = A @ W^T.
// 128x64 tile -> grid (32,16) = 512 blocks (2 independent blocks/CU).
// r7-r9 established WO is insensitive to wave count / block count / dbuf
// within +-5 us; keep the best-measured variant.
// ---------------------------------------------------------------------------
__global__ __launch_bounds__(256) void gemm_wo(
    const ushort_t* __restrict__ A,
    const ushort_t* __restrict__ W,
    float* __restrict__ C, float canary)
{
    __shared__ ushort_t As[128 * 32];   // 8 KB
    __shared__ ushort_t Bs[64 * 32];    // 4 KB

    const int lid  = blockIdx.x + (blockIdx.y << 5);   // grid (32,16) = 512
    const int wgid = (lid & 7) * 64 + (lid >> 3);      // bijective XCD swizzle
    const int m0 = (wgid >> 5) << 7;                   // 16 m-tiles of 128
    const int n0 = (wgid & 31) << 6;                   // 32 n-tiles of 64

    const int t = threadIdx.x;
    const int w = t >> 6, lane = t & 63;
    const int ln = lane & 15, qd = lane >> 4;
    const int wrow = (w >> 1) * 64, wcol = (w & 1) * 32;

    const int r0 = t >> 2, c0 = (t & 3) * 8;           // r0 in [0,64)
    const int r1 = (t + 256) >> 2;                     // r1 in [64,128)
    const ushort_t* Ag0 = A + (size_t)(m0 + r0) * DIM + c0;
    const ushort_t* Ag1 = A + (size_t)(m0 + r1) * DIM + c0;
    const ushort_t* Bg0 = W + (size_t)(n0 + r0) * DIM + c0;
    ushort_t* Al0 = As + (size_t)t * 8;
    ushort_t* Al1 = As + (size_t)(t + 256) * 8;
    ushort_t* Bl0 = Bs + (size_t)t * 8;

    f32x4 acc[4][2] = {};

    for (int k0 = 0; k0 < DIM; k0 += BK) {
        if (k0) __syncthreads();
        __builtin_amdgcn_global_load_lds((const AS1 void*)(Ag0 + k0), (AS3 void*)Al0, 16, 0, 0);
        __builtin_amdgcn_global_load_lds((const AS1 void*)(Ag1 + k0), (AS3 void*)Al1, 16, 0, 0);
        __builtin_amdgcn_global_load_lds((const AS1 void*)(Bg0 + k0), (AS3 void*)Bl0, 16, 0, 0);
        __syncthreads();

        bf16x8 af[4], bfr[2];
        #pragma unroll
        for (int i = 0; i < 4; ++i)
            af[i] = *(const bf16x8*)(As + (wrow + i * 16 + ln) * 32 + qd * 8);
        #pragma unroll
        for (int j = 0; j < 2; ++j)
            bfr[j] = *(const bf16x8*)(Bs + (wcol + j * 16 + ln) * 32 + qd * 8);
        #pragma unroll
        for (int i = 0; i < 4; ++i)
            #pragma unroll
            for (int j = 0; j < 2; ++j)
                acc[i][j] = __builtin_amdgcn_mfma_f32_16x16x32_bf16(af[i], bfr[j], acc[i][j], 0, 0, 0);
    }

    #pragma unroll
    for (int i = 0; i < 4; ++i)
        #pragma unroll
        for (int j = 0; j < 2; ++j) {
            const int gn = n0 + wcol + j * 16 + ln;
            const int gm0 = m0 + wrow + i * 16 + qd * 4;
            #pragma unroll
            for (int r = 0; r < 4; ++r)
                C[(size_t)(gm0 + r) * DIM + gn] = scrub(acc[i][j][r], canary);
        }
}

// ---------------------------------------------------------------------------
// Legacy MFMA GEMM, no LDS (ws fallback path only).
// ---------------------------------------------------------------------------
template<bool AF32, bool CF32>
__global__ __launch_bounds__(256) void mfma_gemm(
    const void* __restrict__ Av,
    const float* __restrict__ B0, const float* __restrict__ B1, const float* __restrict__ B2,
    void* __restrict__ C0, void* __restrict__ C1, void* __restrict__ C2,
    int M, float canary)
{
    const int z = blockIdx.z;
    const float* B = (z == 0) ? B0 : (z == 1) ? B1 : B2;
    void*       C = (z == 0) ? C0 : (z == 1) ? C1 : C2;

    const int m0 = blockIdx.y * 128;
    const int n0 = blockIdx.x * 128;
    const int t    = threadIdx.x;
    const int w    = t >> 6;
    const int lane = t & 63;
    const int ln   = lane & 15, qd = lane >> 4;
    const int wrow = (w >> 1) * 64, wcol = (w & 1) * 64;

    size_t aoff[4];
    const float* brow[4];
    #pragma unroll
    for (int i = 0; i < 4; ++i) {
        int gr = m0 + wrow + i * 16 + ln; gr = (gr < M) ? gr : (M - 1);
        aoff[i] = (size_t)gr * DIM + qd * 8;
        brow[i] = B + (size_t)(n0 + wcol + i * 16 + ln) * DIM + qd * 8;
    }

    f32x4 acc[4][4] = {};

    for (int k0 = 0; k0 < DIM; k0 += BK) {
        bf16x8 af[4], bfr[4];
        #pragma unroll
        for (int i = 0; i < 4; ++i) {
            if (AF32) af[i] = cvt8((const float*)Av + aoff[i] + k0);
            else      af[i] = *(const bf16x8*)((const ushort_t*)Av + aoff[i] + k0);
            bfr[i] = cvt8(brow[i] + k0);
        }
        #pragma unroll
        for (int i = 0; i < 4; ++i)
            #pragma unroll
            for (int j = 0; j < 4; ++j)
                acc[i][j] = __builtin_amdgcn_mfma_f32_16x16x32_bf16(af[i], bfr[j], acc[i][j], 0, 0, 0);
    }

    #pragma unroll
    for (int i = 0; i < 4; ++i) {
        #pragma unroll
        for (int j = 0; j < 4; ++j) {
            const int gn = n0 + wcol + j * 16 + ln;
            #pragma unroll
            for (int r = 0; r < 4; ++r) {
                const int gm = m0 + wrow + i * 16 + qd * 4 + r;
                float v = scrub(acc[i][j][r], canary);
                if (gm < M) {
                    if (CF32) ((float*)C)[(size_t)gm * DIM + gn] = v;
                    else      ((ushort_t*)C)[(size_t)gm * DIM + gn] = f2b(v);
                }
            }
        }
    }
}

// ---------------------------------------------------------------------------
// RoPE on bf16 Q and K workspace rows (ws fallback path only).
// ---------------------------------------------------------------------------
__global__ __launch_bounds__(256) void rope_kernel(ushort_t* __restrict__ Qb,
                                                   ushort_t* __restrict__ Kb,
                                                   const float* __restrict__ fc,
                                                   const float* __restrict__ fs,
                                                   float qscale)
{
    int i = blockIdx.x * 256 + threadIdx.x;
    ushort_t* T = blockIdx.y ? Kb : Qb;
    const float sc = blockIdx.y ? 1.0f : qscale;
    int row = i >> 10;
    int p   = i & 1023;
    float c = fc[((row & 1023) << 6) + (p & 63)];
    float s = fs[((row & 1023) << 6) + (p & 63)];
    ushort_t* ptr = T + (size_t)row * DIM + p * 2;
    float xr = b2f(ptr[0]), xi = b2f(ptr[1]);
    ptr[0] = f2b((xr * c - xi * s) * sc);
    ptr[1] = f2b((xr * s + xi * c) * sc);
}

// ---------------------------------------------------------------------------
// MFMA flash attention v2 (r11 config: XCD swizzle + CU-pair qt balance).
// K row-major and V^T dim-major staged via global_load_lds (pre-swizzled
// source + XOR reads), dbuf, ONE barrier per step. Swapped QK^T -> per-lane
// online softmax. setprio(1) around MFMA clusters. Adapter V frags from
// global V^T (pad zeroed).
// ---------------------------------------------------------------------------
__global__ __launch_bounds__(256) void attn_mfma(const ushort_t* __restrict__ Q,
                                                 const ushort_t* __restrict__ Kg,
                                                 const ushort_t* __restrict__ Vt,
                                                 const float* __restrict__ g1,
                                                 const float* __restrict__ g2,
                                                 const int* __restrict__ vsp,
                                                 ushort_t* __restrict__ AO)
{
    __shared__ ushort_t Kls[2][64 * 128];   // 32 KB, dbuf, swizzled
    __shared__ ushort_t Vls[2][128 * 64];   // 32 KB, dbuf, swizzled (V^T tile)
    __shared__ ushort_t Pl[4 * 16 * 72];    // 9 KB, per-wave P rows [q][tok]

    const int blk = blockIdx.x;
    const int wg   = (blk & 7) * 64 + (blk >> 3);   // XCD-locality remap
    const int gidx = wg >> 4;                       // (b,h) group, 4 per XCD
    const int mem  = wg & 15;
    const int qtb  = (mem & 1) ? (mem >> 1) : (15 - (mem >> 1));
    const int qt   = ((gidx >> 1) & 1) ? (15 - qtb) : qtb;   // CU-pair balance
    const int h = gidx & 15;
    const int b = gidx >> 4;
    const int q0  = qt * 64;
    const int nsteps = qt + 1;
    const int t = threadIdx.x;
    const int w = t >> 6, lane = t & 63;
    const int ln = lane & 15, g = lane >> 4;
    const int hb = h * HD;
    const size_t kvb = (size_t)b << 10;     // batch token base
    const int vs = *vsp;
    const float g2h = g2[h];
    const float ag  = tanhf(g1[h]);
    const int gq = q0 + w * 16 + ln;        // this lane's query row (in-batch)

    const ushort_t* qrow = Q + (kvb + gq) * DIM + hb;
    bf16x8 qf[4];
    #pragma unroll
    for (int c = 0; c < 4; ++c) qf[c] = *(const bf16x8*)(qrow + g * 8 + 32 * c);

    // stage K tile [64 tok][128 d] and V^T tile [128 d][64 tok], both with
    // inverse-XOR on the global source + linear LDS dest (rule 21).
    auto stage = [&](int bi, int k0) {
        #pragma unroll
        for (int p = 0; p < 4; ++p) {
            int i = t + 256 * p;
            int kr = i >> 4, ks = (i & 15) ^ (kr & 7);
            __builtin_amdgcn_global_load_lds(
                (const AS1 void*)(Kg + (kvb + k0 + kr) * DIM + hb + ks * 8),
                (AS3 void*)(&Kls[bi][i * 8]), 16, 0, 0);
        }
        #pragma unroll
        for (int p = 0; p < 4; ++p) {
            int i = t + 256 * p;
            int vr = i >> 3, vsl = (i & 7) ^ (vr & 7);
            __builtin_amdgcn_global_load_lds(
                (const AS1 void*)(Vt + (size_t)(hb + vr) * VTP + kvb + k0 + vsl * 8),
                (AS3 void*)(&Vls[bi][i * 8]), 16, 0, 0);
        }
    };

    stage(0, 0);

    f32x4 oa[8] = {};                       // O^T: oa[dt][r] = O[q][dt*16+g*4+r]
    float m_run = -1e30f, l_run = 0.f;
    ushort_t* Plw = Pl + w * (16 * 72) + ln * 72;

    for (int s = 0; s < nsteps; ++s) {
        const int k0 = s * 64;
        const int cur = s & 1;
        __syncthreads();                    // buf[cur] loads drained; all waves done with buf[cur^1]
        if (s + 1 < nsteps) stage(cur ^ 1, k0 + 64);

        // ---- QK^T (swapped): S^T[tok][q] ----
        f32x4 sc[4] = {};
        __builtin_amdgcn_s_setprio(1);
        #pragma unroll
        for (int mt = 0; mt < 4; ++mt) {
            const int krow = ln + 16 * mt;
            const ushort_t* krp = &Kls[cur][krow * 128];
            #pragma unroll
            for (int c = 0; c < 4; ++c) {
                bf16x8 kf = *(const bf16x8*)(krp + ((8 * g + 32 * c) ^ ((krow & 7) << 3)));
                sc[mt] = __builtin_amdgcn_mfma_f32_16x16x32_bf16(kf, qf[c], sc[mt], 0, 0, 0);
            }
        }
        __builtin_amdgcn_s_setprio(0);

        // ---- mask + online softmax (lane q = ln; tok = k0+mt*16+g*4+r) ----
        float mloc = -3e38f;
        #pragma unroll
        for (int mt = 0; mt < 4; ++mt)
            #pragma unroll
            for (int r = 0; r < 4; ++r) {
                int gk = k0 + mt * 16 + g * 4 + r;
                float v = sc[mt][r];
                if (gk > gq) v -= 1e9f;                                        // causal
                if (gk >= vs && gk < vs + MAXF && gq >= vs + MAXF) v += g2h;   // gate2
                sc[mt][r] = v;
                mloc = fmaxf(mloc, v);
            }
        mloc = fmaxf(mloc, __shfl_xor(mloc, 16));
        mloc = fmaxf(mloc, __shfl_xor(mloc, 32));
        const float m_new = fmaxf(m_run, mloc);
        const float alpha = __expf(m_run - m_new);
        float psum = 0.f;
        #pragma unroll
        for (int mt = 0; mt < 4; ++mt) {
            float p0 = __expf(sc[mt][0] - m_new);
            float p1 = __expf(sc[mt][1] - m_new);
            float p2 = __expf(sc[mt][2] - m_new);
            float p3 = __expf(sc[mt][3] - m_new);
            psum += (p0 + p1) + (p2 + p3);
            uint2 pw_;
            pw_.x = (unsigned)f2b(p0) | ((unsigned)f2b(p1) << 16);
            pw_.y = (unsigned)f2b(p2) | ((unsigned)f2b(p3) << 16);
            *(uint2*)(Plw + mt * 16 + g * 4) = pw_;
        }
        psum += __shfl_xor(psum, 16);
        psum += __shfl_xor(psum, 32);
        l_run = l_run * alpha + psum;
        m_run = m_new;
        #pragma unroll
        for (int i = 0; i < 8; ++i) {
            oa[i][0] *= alpha; oa[i][1] *= alpha; oa[i][2] *= alpha; oa[i][3] *= alpha;
        }

        // ---- PV: O^T[d][q] += V^T-frag x P-frag (tok chunks kc=0,1) ----
        bf16x8 pf0 = *(const bf16x8*)(Plw + 8 * g);
        bf16x8 pf1 = *(const bf16x8*)(Plw + 32 + 8 * g);
        __builtin_amdgcn_s_setprio(1);
        #pragma unroll
        for (int dt = 0; dt < 8; ++dt) {
            const int vrow = dt * 16 + ln;
            const ushort_t* vrp = &Vls[cur][vrow * 64];
            bf16x8 vf0 = *(const bf16x8*)(vrp + ((g     ^ (vrow & 7)) * 8));
            bf16x8 vf1 = *(const bf16x8*)(vrp + (((g+4) ^ (vrow & 7)) * 8));
            oa[dt] = __builtin_amdgcn_mfma_f32_16x16x32_bf16(vf0, pf0, oa[dt], 0, 0, 0);
            oa[dt] = __builtin_amdgcn_mfma_f32_16x16x32_bf16(vf1, pf1, oa[dt], 0, 0, 0);
        }
        __builtin_amdgcn_s_setprio(0);
    }

    const float invl = 1.f / l_run;
    #pragma unroll
    for (int i = 0; i < 8; ++i) {
        oa[i][0] *= invl; oa[i][1] *= invl; oa[i][2] *= invl; oa[i][3] *= invl;
    }

    // ---- adapter: tokens 2048..2057 (+zeroed pad), separate softmax ----
    const ushort_t* karow = Kg + (size_t)(2048 + (ln < 10 ? ln : 9)) * DIM + hb;
    f32x4 sa4 = {};
    #pragma unroll
    for (int c = 0; c < 4; ++c) {
        bf16x8 kf = *(const bf16x8*)(karow + 8 * g + 32 * c);
        sa4 = __builtin_amdgcn_mfma_f32_16x16x32_bf16(kf, qf[c], sa4, 0, 0, 0);
    }
    float am = -3e38f;
    float pa[4];
    #pragma unroll
    for (int r = 0; r < 4; ++r) {
        int kl = g * 4 + r;
        pa[r] = (kl < 10) ? sa4[r] : -1e30f;
        am = fmaxf(am, pa[r]);
    }
    am = fmaxf(am, __shfl_xor(am, 16));
    am = fmaxf(am, __shfl_xor(am, 32));
    float asum = 0.f;
    #pragma unroll
    for (int r = 0; r < 4; ++r) { pa[r] = __expf(pa[r] - am); asum += pa[r]; }
    asum += __shfl_xor(asum, 16);
    asum += __shfl_xor(asum, 32);
    const float coef = ag / asum;
    {
        uint2 pw_;
        pw_.x = (unsigned)f2b(pa[0] * coef) | ((unsigned)f2b(pa[1] * coef) << 16);
        pw_.y = (unsigned)f2b(pa[2] * coef) | ((unsigned)f2b(pa[3] * coef) << 16);
        *(uint2*)(Plw + g * 4) = pw_;
        uint2 z2; z2.x = 0; z2.y = 0;
        *(uint2*)(Plw + 16 + g * 4) = z2;   // zero P[16..31]: MFMA reads k=0..31
    }
    bf16x8 paf = *(const bf16x8*)(Plw + 8 * g);
    #pragma unroll
    for (int dt = 0; dt < 8; ++dt) {
        const ushort_t* varow = Vt + (size_t)(hb + dt * 16 + ln) * VTP + 2048;
        bf16x8 vfa = *(const bf16x8*)(varow + 8 * g);
        oa[dt] = __builtin_amdgcn_mfma_f32_16x16x32_bf16(vfa, paf, oa[dt], 0, 0, 0);
    }

    ushort_t* outp = AO + (kvb + gq) * DIM + hb;
    #pragma unroll
    for (int dt = 0; dt < 8; ++dt) {
        ushort4 ov;
        ov.x = f2b(scrub(oa[dt][0], 1e8f));
        ov.y = f2b(scrub(oa[dt][1], 1e8f));
        ov.z = f2b(scrub(oa[dt][2], 1e8f));
        ov.w = f2b(scrub(oa[dt][3], 1e8f));
        *(ushort4*)(outp + dt * 16 + g * 4) = ov;
    }
}

// ---------------------------------------------------------------------------
// Legacy scalar flash attention (ws fallback path only).
// ---------------------------------------------------------------------------
__global__ __launch_bounds__(256) void attn_kernel(const ushort_t* __restrict__ Q,
                                                   const ushort_t* __restrict__ Kg,
                                                   const ushort_t* __restrict__ Vg,
                                                   const float* __restrict__ g1,
                                                   const float* __restrict__ g2,
                                                   const int* __restrict__ vsp,
                                                   ushort_t* __restrict__ AO)
{
    __shared__ float Qs[32 * 132];
    __shared__ float Ks[32 * 132];
    __shared__ float Vs[32 * 132];
    __shared__ float Ps[32 * 32];

    const int blk = blockIdx.x;
    const int q0  = (31 - (blk & 31)) * 32;
    const int h   = blk >> 5;
    const int t   = threadIdx.x;
    const int qi  = t >> 3;
    const int l8  = t & 7;
    const int vs  = *vsp;
    const int g_q = q0 + qi;
    const float scale = 0.08838834764831845f;
    const float g2h = g2[h];
    const float ag  = tanhf(g1[h]);

    #pragma unroll
    for (int p = 0; p < 4; ++p) {
        int idx = (p * 256 + t) * 4;
        int r = idx >> 7, d = idx & 127;
        ushort4 q4 = *(const ushort4*)(Q + (size_t)(q0 + r) * DIM + h * HD + d);
        *(float4*)(Qs + r * 132 + d) = make_float4(b2f(q4.x), b2f(q4.y), b2f(q4.z), b2f(q4.w));
    }

    float o[16];
    #pragma unroll
    for (int i = 0; i < 16; ++i) o[i] = 0.f;
    float m_run = -1e30f, l_run = 0.f;

    for (int k0 = 0; k0 <= q0 + 31; k0 += 32) {
        __syncthreads();
        #pragma unroll
        for (int p = 0; p < 4; ++p) {
            int idx = (p * 256 + t) * 4;
            int r = idx >> 7, d = idx & 127;
            size_t goff = (size_t)(k0 + r) * DIM + h * HD + d;
            ushort4 k4 = *(const ushort4*)(Kg + goff);
            ushort4 v4 = *(const ushort4*)(Vg + goff);
            *(float4*)(Ks + r * 132 + d) = make_float4(b2f(k4.x), b2f(k4.y), b2f(k4.z), b2f(k4.w));
            *(float4*)(Vs + r * 132 + d) = make_float4(b2f(v4.x), b2f(v4.y), b2f(v4.z), b2f(v4.w));
        }
        __syncthreads();

        float s[4];
        #pragma unroll
        for (int jj = 0; jj < 4; ++jj) s[jj] = 0.f;
        #pragma unroll 4
        for (int d = 0; d < 128; d += 4) {
            const float4 qv = *(const float4*)(Qs + qi * 132 + d);
            #pragma unroll
            for (int jj = 0; jj < 4; ++jj) {
                const float4 kv = *(const float4*)(Ks + (l8 + 8 * jj) * 132 + d);
                s[jj] += qv.x * kv.x + qv.y * kv.y + qv.z * kv.z + qv.w * kv.w;
            }
        }
        float mloc = -1e30f;
        #pragma unroll
        for (int jj = 0; jj < 4; ++jj) {
            int gk = k0 + l8 + 8 * jj;
            float sv = s[jj] * scale;
            if (gk > g_q) sv -= 1e9f;
            if (gk >= vs && gk < vs + MAXF && g_q >= vs + MAXF) sv += g2h;
            s[jj] = sv;
            mloc = fmaxf(mloc, sv);
        }
        mloc = fmaxf(mloc, __shfl_xor(mloc, 1));
        mloc = fmaxf(mloc, __shfl_xor(mloc, 2));
        mloc = fmaxf(mloc, __shfl_xor(mloc, 4));
        const float m_new = fmaxf(m_run, mloc);
        const float alpha = expf(m_run - m_new);
        float psum = 0.f;
        #pragma unroll
        for (int jj = 0; jj < 4; ++jj) {
            float pv = expf(s[jj] - m_new);
            psum += pv;
            Ps[qi * 32 + l8 + 8 * jj] = pv;
        }
        psum += __shfl_xor(psum, 1);
        psum += __shfl_xor(psum, 2);
        psum += __shfl_xor(psum, 4);
        l_run = l_run * alpha + psum;
        m_run = m_new;
        #pragma unroll
        for (int i = 0; i < 16; ++i) o[i] *= alpha;
        __syncthreads();

        #pragma unroll 4
        for (int kk = 0; kk < 32; ++kk) {
            const float pp = Ps[qi * 32 + kk];
            const float* vr = Vs + kk * 132 + l8 * 4;
            #pragma unroll
            for (int jj = 0; jj < 4; ++jj) {
                const float4 v4 = *(const float4*)(vr + jj * 32);
                o[jj*4+0] = fmaf(pp, v4.x, o[jj*4+0]);
                o[jj*4+1] = fmaf(pp, v4.y, o[jj*4+1]);
                o[jj*4+2] = fmaf(pp, v4.z, o[jj*4+2]);
                o[jj*4+3] = fmaf(pp, v4.w, o[jj*4+3]);
            }
        }
    }

    const float invl = 1.f / l_run;
    #pragma unroll
    for (int i = 0; i < 16; ++i) o[i] *= invl;

    __syncthreads();
    #pragma unroll
    for (int p = 0; p < 2; ++p) {
        int idx = p * 256 + t;
        if (idx < 320) {
            int fi = idx * 4; int r = fi >> 7; int d = fi & 127;
            size_t goff = (size_t)(SEQQ + r) * DIM + h * HD + d;
            ushort4 k4 = *(const ushort4*)(Kg + goff);
            ushort4 v4 = *(const ushort4*)(Vg + goff);
            *(float4*)(Ks + r * 132 + d) = make_float4(b2f(k4.x), b2f(k4.y), b2f(k4.z), b2f(k4.w));
            *(float4*)(Vs + r * 132 + d) = make_float4(b2f(v4.x), b2f(v4.y), b2f(v4.z), b2f(v4.w));
        }
    }
    __syncthreads();
    float sa[2] = {-1e30f, -1e30f};
    #pragma unroll
    for (int jj = 0; jj < 2; ++jj) {
        int kk = l8 + 8 * jj;
        if (kk < AL) {
            float acc = 0.f;
            #pragma unroll 4
            for (int d = 0; d < 128; d += 4) {
                const float4 qv = *(const float4*)(Qs + qi * 132 + d);
                const float4 kv = *(const float4*)(Ks + kk * 132 + d);
                acc += qv.x * kv.x + qv.y * kv.y + qv.z * kv.z + qv.w * kv.w;
            }
            sa[jj] = acc * scale;
        }
    }
    float am = fmaxf(sa[0], sa[1]);
    am = fmaxf(am, __shfl_xor(am, 1));
    am = fmaxf(am, __shfl_xor(am, 2));
    am = fmaxf(am, __shfl_xor(am, 4));
    float pa0 = expf(sa[0] - am);
    float pa1 = (l8 < 2) ? expf(sa[1] - am) : 0.f;
    float asum = pa0 + pa1;
    asum += __shfl_xor(asum, 1);
    asum += __shfl_xor(asum, 2);
    asum += __shfl_xor(asum, 4);
    const float coef = ag / asum;
    Ps[qi * 32 + l8] = pa0 * coef;
    if (l8 < 2) Ps[qi * 32 + 8 + l8] = pa1 * coef;
    __syncthreads();
    #pragma unroll
    for (int kk = 0; kk < AL; ++kk) {
        const float pp = Ps[qi * 32 + kk];
        const float* vr = Vs + kk * 132 + l8 * 4;
        #pragma unroll
        for (int jj = 0; jj < 4; ++jj) {
            const float4 v4 = *(const float4*)(vr + jj * 32);
            o[jj*4+0] = fmaf(pp, v4.x, o[jj*4+0]);
            o[jj*4+1] = fmaf(pp, v4.y, o[jj*4+1]);
            o[jj*4+2] = fmaf(pp, v4.z, o[jj*4+2]);
            o[jj*4+3] = fmaf(pp, v4.w, o[jj*4+3]);
        }
    }

    ushort_t* outp = AO + (size_t)g_q * DIM + h * HD + l8 * 4;
    #pragma unroll
    for (int jj = 0; jj < 4; ++jj) {
        ushort4 ov;
        ov.x = f2b(scrub(o[jj*4+0], 1e8f));
        ov.y = f2b(scrub(o[jj*4+1], 1e8f));
        ov.z = f2b(scrub(o[jj*4+2], 1e8f));
        ov.w = f2b(scrub(o[jj*4+3], 1e8f));
        *(ushort4*)(outp + jj * 32) = ov;
    }
}

// ---------------------------------------------------------------------------
extern "C" void kernel_launch(void* const* d_in, const int* in_sizes, int n_in,
                              void* d_out, int out_size, void* d_ws, size_t ws_size,
                              hipStream_t stream)
{
    const float* x   = (const float*)d_in[0];
    const float* adp = (const float*)d_in[1];
    /* d_in[2] mask: recomputed analytically */
    const float* fc  = (const float*)d_in[3];
    const float* fs  = (const float*)d_in[4];
    const float* wq  = (const float*)d_in[5];
    const float* wk  = (const float*)d_in[6];
    const float* wv  = (const float*)d_in[7];
    const float* wo  = (const float*)d_in[8];
    const float* g1  = (const float*)d_in[9];
    const float* g2  = (const float*)d_in[10];
    const int*   vsp = (const int*)d_in[11];

    float* out = (float*)d_out;

    const size_t rows2 = (size_t)BSZ * SEQQ;         // 2048
    const size_t qe2 = rows2 * DIM;                  // Qb (both batches)
    const size_t ke2 = (rows2 + AL) * DIM;           // Kb: 2058 rows token-major
    const size_t vte = (size_t)DIM * VTP;            // V^T [2048][2080]
    const size_t we  = (size_t)DIM * DIM;
    const size_t xe  = (size_t)BSZ * SEQQ * DIM;
    const size_t need = (qe2 + ke2 + vte + xe + 4 * we) * sizeof(ushort_t);  // ~67.3 MB

    if (ws_size >= need) {
        // ---- fast path ----
        // ws: Qb[2048](alias AO) | Kb[2058 rows] | VtG[2048][2080] | Xb | 4 weights
        ushort_t* Qb  = (ushort_t*)d_ws;
        ushort_t* Kb  = Qb + qe2;
        ushort_t* VtG = Kb + ke2;
        ushort_t* Xb  = VtG + vte;
        ushort_t* Wqb = Xb + xe;
        ushort_t* Wkb = Wqb + we;
        ushort_t* Wvb = Wkb + we;
        ushort_t* Wob = Wvb + we;

        cvt5<<<dim3(2048, 5), 256, 0, stream>>>(wq, wk, wv, wo, x,
                                                Wqb, Wkb, Wvb, Wob, Xb);

        // adapter K rows 2048..2057 (token-major) + V^T cols 2048..2057 (+pad)
        adapter_gemm<<<512, 256, 0, stream>>>(adp, Wkb, Wvb,
                                              Kb + rows2 * DIM, VtG,
                                              100.0f);

        // fused QKV for both batches (M=2048); z=0/1 rope fused, z=2 V^T.
        // BK=64 + XOR-swizzled LDS (r12).
        gemm_bt<0><<<dim3(16, 16, 3), 256, 0, stream>>>(
            Xb, Wqb, Wkb, Wvb, Qb, Kb, VtG,
            fc, fs, 0.08838834764831845f, 1e5f);

        // MFMA flash attention, both batches, one launch (CU-pair balanced).
        attn_mfma<<<512, 256, 0, stream>>>(Qb, Kb, VtG, g1, g2, vsp, Qb /* AO alias */);

        // final projection -> fp32 d_out (r8 best-measured config). canary 1e12.
        gemm_wo<<<dim3(32, 16), 256, 0, stream>>>(Qb, Wob, out, 1e12f);
    } else {
        // ---- fallback: round-1 verified per-batch path ----
        const size_t qe = (size_t)SEQQ * DIM;
        const size_t ke = (size_t)KVROWS * DIM;
        ushort_t* Qb = (ushort_t*)d_ws;
        ushort_t* Kb = Qb + qe;
        ushort_t* Vb = Kb + ke;

        mfma_gemm<true, false><<<dim3(16, 1, 2), 256, 0, stream>>>(
            adp, wk, wv, wv,
            Kb + qe, Vb + qe, Vb,
            AL, 100.0f);

        for (int b = 0; b < BSZ; ++b) {
            const long xo = (long)b * SEQQ * DIM;
            mfma_gemm<true, false><<<dim3(16, 8, 3), 256, 0, stream>>>(
                x + xo, wq, wk, wv, Qb, Kb, Vb, SEQQ, 1e5f);

            rope_kernel<<<dim3(4096, 2), 256, 0, stream>>>(Qb, Kb, fc, fs, 1.0f);

            attn_kernel<<<NH * (SEQQ / 32), 256, 0, stream>>>(Qb, Kb, Vb, g1, g2, vsp, Qb);

            mfma_gemm<false, true><<<dim3(16, 8, 1), 256, 0, stream>>>(
                Qb, wo, wo, wo, out + xo, out + xo, out + xo, SEQQ, 1e12f);
        }
    }
}

// Round 13
// 281.503 us; speedup vs baseline: 1.0442x; 1.0442x over previous
//
#include <hip/hip_runtime.h>
#include <math.h>

#define DIM   2048
#define NH    16
#define HD    128
#define SEQQ  1024
#define BSZ   2
#define AL    10
#define MAXF  10
#define KVROWS (SEQQ + AL)   /* legacy per-batch K/V rows (fallback path) */
#define BK    32
#define VTP   2080           /* V^T pitch: 2048 tok + 10 adapter + 22 zero pad
                                (adapter MFMA reads tokens up to 2079) */

typedef unsigned short ushort_t;
typedef __bf16   bf16x8 __attribute__((ext_vector_type(8)));
typedef float    f32x4  __attribute__((ext_vector_type(4)));
typedef ushort_t us8    __attribute__((ext_vector_type(8)));

#define AS1 __attribute__((address_space(1)))
#define AS3 __attribute__((address_space(3)))

__device__ __forceinline__ float b2f(ushort_t u) {
    return __uint_as_float(((unsigned int)u) << 16);
}
__device__ __forceinline__ ushort_t f2b(float f) {
    unsigned int u = __float_as_uint(f);
    u += 0x7fffu + ((u >> 16) & 1u);   // round-to-nearest-even
    return (ushort_t)(u >> 16);
}
// non-finite check immune to fast-math: exponent all-ones => Inf or NaN
__device__ __forceinline__ float scrub(float v, float canary) {
    return ((__float_as_uint(v) & 0x7f800000u) == 0x7f800000u) ? canary : v;
}
// 8 consecutive fp32 -> bf16x8 fragment (RNE)
__device__ __forceinline__ bf16x8 cvt8(const float* p) {
    float4 a = *(const float4*)p;
    float4 b = *(const float4*)(p + 4);
    us8 u;
    u[0] = f2b(a.x); u[1] = f2b(a.y); u[2] = f2b(a.z); u[3] = f2b(a.w);
    u[4] = f2b(b.x); u[5] = f2b(b.y); u[6] = f2b(b.z); u[7] = f2b(b.w);
    return *(bf16x8*)&u;
}

// ---------------------------------------------------------------------------
// fp32 -> bf16 bulk convert, 8 elems/thread, 5 arrays (blockIdx.y selects).
// Each array exactly 4,194,304 elems -> grid (2048, 5), no bounds check.
// ---------------------------------------------------------------------------
__global__ __launch_bounds__(256) void cvt5(
    const float* __restrict__ s0, const float* __restrict__ s1,
    const float* __restrict__ s2, const float* __restrict__ s3,
    const float* __restrict__ s4,
    ushort_t* __restrict__ d0, ushort_t* __restrict__ d1,
    ushort_t* __restrict__ d2, ushort_t* __restrict__ d3,
    ushort_t* __restrict__ d4)
{
    const int y = blockIdx.y;
    const float* s = (y == 0) ? s0 : (y == 1) ? s1 : (y == 2) ? s2 : (y == 3) ? s3 : s4;
    ushort_t*    d = (y == 0) ? d0 : (y == 1) ? d1 : (y == 2) ? d2 : (y == 3) ? d3 : d4;
    size_t i = (size_t)blockIdx.x * 256 + threadIdx.x;   // group-of-8 index
    float4 a = ((const float4*)s)[2 * i];
    float4 b = ((const float4*)s)[2 * i + 1];
    us8 u;
    u[0] = f2b(a.x); u[1] = f2b(a.y); u[2] = f2b(a.z); u[3] = f2b(a.w);
    u[4] = f2b(b.x); u[5] = f2b(b.y); u[6] = f2b(b.z); u[7] = f2b(b.w);
    *(us8*)(d + i * 8) = u;
}

// ---------------------------------------------------------------------------
// Adapter projection. z=0: K rows (token-major, rows 2048..2057 of Kb).
// z=1: V -> V^T global [dim][VTP], tokens 2048..2057, AND zeroes pad tokens
// 2058..2079 (required: attn reads them as MFMA operands; ws is poisoned).
// 512 blocks; block stages adapter in LDS bf16, wave dots one weight row.
// ---------------------------------------------------------------------------
__global__ __launch_bounds__(256) void adapter_gemm(
    const float* __restrict__ adp,
    const ushort_t* __restrict__ Wkb, const ushort_t* __restrict__ Wvb,
    ushort_t* __restrict__ Ko, ushort_t* __restrict__ VtO,
    float canary)
{
    __shared__ ushort_t Al[AL * DIM];   // 40 KB

    const int t = threadIdx.x;
    #pragma unroll
    for (int p = 0; p < 10; ++p) {      // 2560 groups of 8 / 256 threads
        int i = p * 256 + t;
        const float* sp = adp + i * 8;
        float4 a = *(const float4*)sp;
        float4 b = *(const float4*)(sp + 4);
        us8 u;
        u[0] = f2b(a.x); u[1] = f2b(a.y); u[2] = f2b(a.z); u[3] = f2b(a.w);
        u[4] = f2b(b.x); u[5] = f2b(b.y); u[6] = f2b(b.z); u[7] = f2b(b.w);
        *(us8*)(Al + i * 8) = u;
    }
    __syncthreads();

    const int z = blockIdx.x >> 8;
    const ushort_t* W = z ? Wvb : Wkb;
    const int nbase = (blockIdx.x & 255) * 8;
    const int w = t >> 6, lane = t & 63;

    #pragma unroll
    for (int nn = 0; nn < 2; ++nn) {
        const int n = nbase + w * 2 + nn;
        const ushort_t* wr = W + (size_t)n * DIM;
        float acc[AL] = {};
        #pragma unroll
        for (int c = 0; c < 4; ++c) {
            const int k = c * 512 + lane * 8;
            us8 b8 = *(const us8*)(wr + k);
            float bf[8];
            #pragma unroll
            for (int j = 0; j < 8; ++j) bf[j] = b2f(b8[j]);
            #pragma unroll
            for (int m = 0; m < AL; ++m) {
                us8 a8 = *(const us8*)(Al + m * DIM + k);
                #pragma unroll
                for (int j = 0; j < 8; ++j)
                    acc[m] = fmaf(b2f(a8[j]), bf[j], acc[m]);
            }
        }
        #pragma unroll
        for (int m = 0; m < AL; ++m) {
            float v = acc[m];
            v += __shfl_xor(v, 1);  v += __shfl_xor(v, 2);
            v += __shfl_xor(v, 4);  v += __shfl_xor(v, 8);
            v += __shfl_xor(v, 16); v += __shfl_xor(v, 32);
            if (lane == 0) {
                ushort_t ov = f2b(scrub(v, canary));
                if (z) VtO[(size_t)n * VTP + 2048 + m] = ov;
                else   Ko[(size_t)m * DIM + n] = ov;
            }
        }
        if (z && lane < 22) VtO[(size_t)n * VTP + 2058 + lane] = 0;  // zero pad
    }
}

// ---------------------------------------------------------------------------
// m97-structure GEMM (r11 config -- best measured total): C[M,2048] = A*B^T,
// fp32 acc, 128x128 tile, BK=32; global_load_lds -> linear LDS, ds_read_b128
// frags. r12 lesson: BK=64+swizzle zeroed bank conflicts but raised HBM
// traffic / lowered occupancy for net -2 on QKV and worse total; at 3
// blocks/CU the inter-block overlap already hides LDS conflicts -> keep r11.
// Grid (16,16,NZ), (256*NZ)%8==0 (bijective XCD swizzle).
// MODE 0: z=0 Q (RoPE+qscale fused), z=1 K (RoPE fused), z=2 V^T [dim][VTP].
// ---------------------------------------------------------------------------
template<int MODE>
__global__ __launch_bounds__(256) void gemm_bt(
    const ushort_t* __restrict__ A,
    const ushort_t* __restrict__ B0, const ushort_t* __restrict__ B1, const ushort_t* __restrict__ B2,
    void* __restrict__ C0, void* __restrict__ C1, void* __restrict__ C2,
    const float* __restrict__ fc, const float* __restrict__ fs,
    float qscale, float canary)
{
    __shared__ ushort_t As[128 * 32];
    __shared__ ushort_t Bs[128 * 32];

    // bijective XCD swizzle: nwg = 256*gridDim.z, chunk = nwg/8 per XCD
    const int lid  = blockIdx.x + (blockIdx.y << 4) + (blockIdx.z << 8);
    const int cpx  = (int)(gridDim.z << 5);          // (256*z)/8
    const int wgid = (lid & 7) * cpx + (lid >> 3);
    const int z    = wgid >> 8;
    const int rem  = wgid & 255;
    const int m0   = (rem >> 4) << 7;
    const int n0   = (rem & 15) << 7;

    const ushort_t* B = (z == 0) ? B0 : (z == 1) ? B1 : B2;
    void*           C = (z == 0) ? C0 : (z == 1) ? C1 : C2;

    const int t = threadIdx.x;
    const int w = t >> 6, lane = t & 63;
    const int ln = lane & 15, qd = lane >> 4;
    const int wrow = (w >> 1) * 64, wcol = (w & 1) * 64;

    const int r0 = t >> 2, c0 = (t & 3) * 8;
    const int r1 = (t + 256) >> 2;
    const ushort_t* Ag0 = A + (size_t)(m0 + r0) * DIM + c0;
    const ushort_t* Ag1 = A + (size_t)(m0 + r1) * DIM + c0;
    const ushort_t* Bg0 = B + (size_t)(n0 + r0) * DIM + c0;
    const ushort_t* Bg1 = B + (size_t)(n0 + r1) * DIM + c0;
    ushort_t* Al0 = As + (size_t)t * 8;
    ushort_t* Al1 = As + (size_t)(t + 256) * 8;
    ushort_t* Bl0 = Bs + (size_t)t * 8;
    ushort_t* Bl1 = Bs + (size_t)(t + 256) * 8;

    f32x4 acc[4][4] = {};

    for (int k0 = 0; k0 < DIM; k0 += BK) {
        if (k0) __syncthreads();
        __builtin_amdgcn_global_load_lds((const AS1 void*)(Ag0 + k0), (AS3 void*)Al0, 16, 0, 0);
        __builtin_amdgcn_global_load_lds((const AS1 void*)(Ag1 + k0), (AS3 void*)Al1, 16, 0, 0);
        __builtin_amdgcn_global_load_lds((const AS1 void*)(Bg0 + k0), (AS3 void*)Bl0, 16, 0, 0);
        __builtin_amdgcn_global_load_lds((const AS1 void*)(Bg1 + k0), (AS3 void*)Bl1, 16, 0, 0);
        __syncthreads();

        bf16x8 af[4], bfr[4];
        #pragma unroll
        for (int i = 0; i < 4; ++i) {
            af[i]  = *(const bf16x8*)(As + (wrow + i * 16 + ln) * 32 + qd * 8);
            bfr[i] = *(const bf16x8*)(Bs + (wcol + i * 16 + ln) * 32 + qd * 8);
        }
        #pragma unroll
        for (int i = 0; i < 4; ++i)
            #pragma unroll
            for (int j = 0; j < 4; ++j)
                acc[i][j] = __builtin_amdgcn_mfma_f32_16x16x32_bf16(af[i], bfr[j], acc[i][j], 0, 0, 0);
    }

    const float rsc = (MODE == 0 && z == 0) ? qscale : 1.0f;

    #pragma unroll
    for (int i = 0; i < 4; ++i) {
        #pragma unroll
        for (int j = 0; j < 4; ++j) {
            const int gn = n0 + wcol + j * 16 + ln;
            const int gm0 = m0 + wrow + i * 16 + qd * 4;
            if (MODE == 0 && z == 2) {
                // V^T store: 4 consecutive tokens (r) in one ushort4
                ushort4 ov;
                ov.x = f2b(scrub(acc[i][j][0], canary));
                ov.y = f2b(scrub(acc[i][j][1], canary));
                ov.z = f2b(scrub(acc[i][j][2], canary));
                ov.w = f2b(scrub(acc[i][j][3], canary));
                *(ushort4*)((ushort_t*)C + (size_t)gn * VTP + gm0) = ov;
            } else if (MODE == 0) {
                // z=0/1: fused RoPE (+qscale for Q). Pair partner in lane^1.
                const int fidx = (gn & 127) >> 1;
                #pragma unroll
                for (int r = 0; r < 4; ++r) {
                    const int gm = gm0 + r;
                    float v = scrub(acc[i][j][r], canary);
                    float po = __shfl_xor(v, 1);
                    const int fo = ((gm & 1023) << 6) + fidx;
                    float c = fc[fo], s = fs[fo];
                    float ov = (ln & 1) ? (po * s + v * c) : (v * c - po * s);
                    ((ushort_t*)C)[(size_t)gm * DIM + gn] = f2b(ov * rsc);
                }
            } else {
                #pragma unroll
                for (int r = 0; r < 4; ++r) {
                    float v = scrub(acc[i][j][r], canary);
                    ((float*)C)[(size_t)(gm0 + r) * DIM + gn] = v;
                }
            }
        }
    }
}

// ---------------------------------------------------------------------------
// WO projection v2 (r13): C[2048,2048] fp32 = A @ W^T. 128x64 tile, 512
// blocks (2/CU), 4 waves -- now with BK=64 + both-sides XOR swizzle
// (r12-proven recipe). Rationale: WO at 1-2 blocks/CU has NOTHING hiding
// its LDS-read latency (r7-r9: waves/blocks/dbuf all null), and the old
// [*, 32] layout is an 8-way read conflict (~2.9x per ds_read, G4) sitting
// DIRECTLY on the critical path. Row stride 128B -> rows span all 32 banks,
// 16 frag lanes land 2-way (free); barrier drains halve 64 -> 32.
// LDS 24 KB keeps 2 blocks/CU. Output is plain fp32 rows (no VTP scatter),
// so r12's write-amplification side-effect does not apply here.
// ---------------------------------------------------------------------------
__global__ __launch_bounds__(256) void gemm_wo(
    const ushort_t* __restrict__ A,
    const ushort_t* __restrict__ W,
    float* __restrict__ C, float canary)
{
    __shared__ ushort_t As[128 * 64];   // 16 KB
    __shared__ ushort_t Bs[64 * 64];    //  8 KB

    const int lid  = blockIdx.x + (blockIdx.y << 5);   // grid (32,16) = 512
    const int wgid = (lid & 7) * 64 + (lid >> 3);      // bijective XCD swizzle
    const int m0 = (wgid >> 5) << 7;                   // 16 m-tiles of 128
    const int n0 = (wgid & 31) << 6;                   // 32 n-tiles of 64

    const int t = threadIdx.x;
    const int w = t >> 6, lane = t & 63;
    const int ln = lane & 15, qd = lane >> 4;
    const int wrow = (w >> 1) * 64, wcol = (w & 1) * 32;

    // staging (rule 21: linear LDS dest + inverse-XOR on the global source):
    // A: 1024 16B-chunks, i = t+256p (p=0..3): row=i>>3, slot=(i&7)^(row&7)
    // B:  512 16B-chunks, i = t+256p (p=0..1): same mapping
    const ushort_t* Agp[4]; ushort_t* Alp[4];
    #pragma unroll
    for (int p = 0; p < 4; ++p) {
        int i = t + 256 * p;
        int row = i >> 3, sl = (i & 7) ^ (row & 7);
        Agp[p] = A + (size_t)(m0 + row) * DIM + sl * 8;
        Alp[p] = As + (size_t)i * 8;
    }
    const ushort_t* Bgp[2]; ushort_t* Blp[2];
    #pragma unroll
    for (int p = 0; p < 2; ++p) {
        int i = t + 256 * p;
        int row = i >> 3, sl = (i & 7) ^ (row & 7);
        Bgp[p] = W + (size_t)(n0 + row) * DIM + sl * 8;
        Blp[p] = Bs + (size_t)i * 8;
    }

    f32x4 acc[4][2] = {};

    for (int k0 = 0; k0 < DIM; k0 += 64) {
        if (k0) __syncthreads();
        #pragma unroll
        for (int p = 0; p < 4; ++p)
            __builtin_amdgcn_global_load_lds((const AS1 void*)(Agp[p] + k0), (AS3 void*)Alp[p], 16, 0, 0);
        #pragma unroll
        for (int p = 0; p < 2; ++p)
            __builtin_amdgcn_global_load_lds((const AS1 void*)(Bgp[p] + k0), (AS3 void*)Blp[p], 16, 0, 0);
        __syncthreads();

        #pragma unroll
        for (int kk = 0; kk < 2; ++kk) {
            bf16x8 af[4], bfr[2];
            #pragma unroll
            for (int i = 0; i < 4; ++i) {
                const int ar = wrow + i * 16 + ln;
                af[i] = *(const bf16x8*)(As + (size_t)ar * 64 + (((kk << 2) + qd) ^ (ar & 7)) * 8);
            }
            #pragma unroll
            for (int j = 0; j < 2; ++j) {
                const int br = wcol + j * 16 + ln;
                bfr[j] = *(const bf16x8*)(Bs + (size_t)br * 64 + (((kk << 2) + qd) ^ (br & 7)) * 8);
            }
            #pragma unroll
            for (int i = 0; i < 4; ++i)
                #pragma unroll
                for (int j = 0; j < 2; ++j)
                    acc[i][j] = __builtin_amdgcn_mfma_f32_16x16x32_bf16(af[i], bfr[j], acc[i][j], 0, 0, 0);
        }
    }

    #pragma unroll
    for (int i = 0; i < 4; ++i)
        #pragma unroll
        for (int j = 0; j < 2; ++j) {
            const int gn = n0 + wcol + j * 16 + ln;
            const int gm0 = m0 + wrow + i * 16 + qd * 4;
            #pragma unroll
            for (int r = 0; r < 4; ++r)
                C[(size_t)(gm0 + r) * DIM + gn] = scrub(acc[i][j][r], canary);
        }
}

// ---------------------------------------------------------------------------
// Legacy MFMA GEMM, no LDS (ws fallback path only).
// ---------------------------------------------------------------------------
template<bool AF32, bool CF32>
__global__ __launch_bounds__(256) void mfma_gemm(
    const void* __restrict__ Av,
    const float* __restrict__ B0, const float* __restrict__ B1, const float* __restrict__ B2,
    void* __restrict__ C0, void* __restrict__ C1, void* __restrict__ C2,
    int M, float canary)
{
    const int z = blockIdx.z;
    const float* B = (z == 0) ? B0 : (z == 1) ? B1 : B2;
    void*       C = (z == 0) ? C0 : (z == 1) ? C1 : C2;

    const int m0 = blockIdx.y * 128;
    const int n0 = blockIdx.x * 128;
    const int t    = threadIdx.x;
    const int w    = t >> 6;
    const int lane = t & 63;
    const int ln   = lane & 15, qd = lane >> 4;
    const int wrow = (w >> 1) * 64, wcol = (w & 1) * 64;

    size_t aoff[4];
    const float* brow[4];
    #pragma unroll
    for (int i = 0; i < 4; ++i) {
        int gr = m0 + wrow + i * 16 + ln; gr = (gr < M) ? gr : (M - 1);
        aoff[i] = (size_t)gr * DIM + qd * 8;
        brow[i] = B + (size_t)(n0 + wcol + i * 16 + ln) * DIM + qd * 8;
    }

    f32x4 acc[4][4] = {};

    for (int k0 = 0; k0 < DIM; k0 += BK) {
        bf16x8 af[4], bfr[4];
        #pragma unroll
        for (int i = 0; i < 4; ++i) {
            if (AF32) af[i] = cvt8((const float*)Av + aoff[i] + k0);
            else      af[i] = *(const bf16x8*)((const ushort_t*)Av + aoff[i] + k0);
            bfr[i] = cvt8(brow[i] + k0);
        }
        #pragma unroll
        for (int i = 0; i < 4; ++i)
            #pragma unroll
            for (int j = 0; j < 4; ++j)
                acc[i][j] = __builtin_amdgcn_mfma_f32_16x16x32_bf16(af[i], bfr[j], acc[i][j], 0, 0, 0);
    }

    #pragma unroll
    for (int i = 0; i < 4; ++i) {
        #pragma unroll
        for (int j = 0; j < 4; ++j) {
            const int gn = n0 + wcol + j * 16 + ln;
            #pragma unroll
            for (int r = 0; r < 4; ++r) {
                const int gm = m0 + wrow + i * 16 + qd * 4 + r;
                float v = scrub(acc[i][j][r], canary);
                if (gm < M) {
                    if (CF32) ((float*)C)[(size_t)gm * DIM + gn] = v;
                    else      ((ushort_t*)C)[(size_t)gm * DIM + gn] = f2b(v);
                }
            }
        }
    }
}

// ---------------------------------------------------------------------------
// RoPE on bf16 Q and K workspace rows (ws fallback path only).
// ---------------------------------------------------------------------------
__global__ __launch_bounds__(256) void rope_kernel(ushort_t* __restrict__ Qb,
                                                   ushort_t* __restrict__ Kb,
                                                   const float* __restrict__ fc,
                                                   const float* __restrict__ fs,
                                                   float qscale)
{
    int i = blockIdx.x * 256 + threadIdx.x;
    ushort_t* T = blockIdx.y ? Kb : Qb;
    const float sc = blockIdx.y ? 1.0f : qscale;
    int row = i >> 10;
    int p   = i & 1023;
    float c = fc[((row & 1023) << 6) + (p & 63)];
    float s = fs[((row & 1023) << 6) + (p & 63)];
    ushort_t* ptr = T + (size_t)row * DIM + p * 2;
    float xr = b2f(ptr[0]), xi = b2f(ptr[1]);
    ptr[0] = f2b((xr * c - xi * s) * sc);
    ptr[1] = f2b((xr * s + xi * c) * sc);
}

// ---------------------------------------------------------------------------
// MFMA flash attention v2 (r11 config: XCD swizzle + CU-pair qt balance).
// K row-major and V^T dim-major staged via global_load_lds (pre-swizzled
// source + XOR reads), dbuf, ONE barrier per step. Swapped QK^T -> per-lane
// online softmax. setprio(1) around MFMA clusters. Adapter V frags from
// global V^T (pad zeroed).
// ---------------------------------------------------------------------------
__global__ __launch_bounds__(256) void attn_mfma(const ushort_t* __restrict__ Q,
                                                 const ushort_t* __restrict__ Kg,
                                                 const ushort_t* __restrict__ Vt,
                                                 const float* __restrict__ g1,
                                                 const float* __restrict__ g2,
                                                 const int* __restrict__ vsp,
                                                 ushort_t* __restrict__ AO)
{
    __shared__ ushort_t Kls[2][64 * 128];   // 32 KB, dbuf, swizzled
    __shared__ ushort_t Vls[2][128 * 64];   // 32 KB, dbuf, swizzled (V^T tile)
    __shared__ ushort_t Pl[4 * 16 * 72];    // 9 KB, per-wave P rows [q][tok]

    const int blk = blockIdx.x;
    const int wg   = (blk & 7) * 64 + (blk >> 3);   // XCD-locality remap
    const int gidx = wg >> 4;                       // (b,h) group, 4 per XCD
    const int mem  = wg & 15;
    const int qtb  = (mem & 1) ? (mem >> 1) : (15 - (mem >> 1));
    const int qt   = ((gidx >> 1) & 1) ? (15 - qtb) : qtb;   // CU-pair balance
    const int h = gidx & 15;
    const int b = gidx >> 4;
    const int q0  = qt * 64;
    const int nsteps = qt + 1;
    const int t = threadIdx.x;
    const int w = t >> 6, lane = t & 63;
    const int ln = lane & 15, g = lane >> 4;
    const int hb = h * HD;
    const size_t kvb = (size_t)b << 10;     // batch token base
    const int vs = *vsp;
    const float g2h = g2[h];
    const float ag  = tanhf(g1[h]);
    const int gq = q0 + w * 16 + ln;        // this lane's query row (in-batch)

    const ushort_t* qrow = Q + (kvb + gq) * DIM + hb;
    bf16x8 qf[4];
    #pragma unroll
    for (int c = 0; c < 4; ++c) qf[c] = *(const bf16x8*)(qrow + g * 8 + 32 * c);

    // stage K tile [64 tok][128 d] and V^T tile [128 d][64 tok], both with
    // inverse-XOR on the global source + linear LDS dest (rule 21).
    auto stage = [&](int bi, int k0) {
        #pragma unroll
        for (int p = 0; p < 4; ++p) {
            int i = t + 256 * p;
            int kr = i >> 4, ks = (i & 15) ^ (kr & 7);
            __builtin_amdgcn_global_load_lds(
                (const AS1 void*)(Kg + (kvb + k0 + kr) * DIM + hb + ks * 8),
                (AS3 void*)(&Kls[bi][i * 8]), 16, 0, 0);
        }
        #pragma unroll
        for (int p = 0; p < 4; ++p) {
            int i = t + 256 * p;
            int vr = i >> 3, vsl = (i & 7) ^ (vr & 7);
            __builtin_amdgcn_global_load_lds(
                (const AS1 void*)(Vt + (size_t)(hb + vr) * VTP + kvb + k0 + vsl * 8),
                (AS3 void*)(&Vls[bi][i * 8]), 16, 0, 0);
        }
    };

    stage(0, 0);

    f32x4 oa[8] = {};                       // O^T: oa[dt][r] = O[q][dt*16+g*4+r]
    float m_run = -1e30f, l_run = 0.f;
    ushort_t* Plw = Pl + w * (16 * 72) + ln * 72;

    for (int s = 0; s < nsteps; ++s) {
        const int k0 = s * 64;
        const int cur = s & 1;
        __syncthreads();                    // buf[cur] loads drained; all waves done with buf[cur^1]
        if (s + 1 < nsteps) stage(cur ^ 1, k0 + 64);

        // ---- QK^T (swapped): S^T[tok][q] ----
        f32x4 sc[4] = {};
        __builtin_amdgcn_s_setprio(1);
        #pragma unroll
        for (int mt = 0; mt < 4; ++mt) {
            const int krow = ln + 16 * mt;
            const ushort_t* krp = &Kls[cur][krow * 128];
            #pragma unroll
            for (int c = 0; c < 4; ++c) {
                bf16x8 kf = *(const bf16x8*)(krp + ((8 * g + 32 * c) ^ ((krow & 7) << 3)));
                sc[mt] = __builtin_amdgcn_mfma_f32_16x16x32_bf16(kf, qf[c], sc[mt], 0, 0, 0);
            }
        }
        __builtin_amdgcn_s_setprio(0);

        // ---- mask + online softmax (lane q = ln; tok = k0+mt*16+g*4+r) ----
        float mloc = -3e38f;
        #pragma unroll
        for (int mt = 0; mt < 4; ++mt)
            #pragma unroll
            for (int r = 0; r < 4; ++r) {
                int gk = k0 + mt * 16 + g * 4 + r;
                float v = sc[mt][r];
                if (gk > gq) v -= 1e9f;                                        // causal
                if (gk >= vs && gk < vs + MAXF && gq >= vs + MAXF) v += g2h;   // gate2
                sc[mt][r] = v;
                mloc = fmaxf(mloc, v);
            }
        mloc = fmaxf(mloc, __shfl_xor(mloc, 16));
        mloc = fmaxf(mloc, __shfl_xor(mloc, 32));
        const float m_new = fmaxf(m_run, mloc);
        const float alpha = __expf(m_run - m_new);
        float psum = 0.f;
        #pragma unroll
        for (int mt = 0; mt < 4; ++mt) {
            float p0 = __expf(sc[mt][0] - m_new);
            float p1 = __expf(sc[mt][1] - m_new);
            float p2 = __expf(sc[mt][2] - m_new);
            float p3 = __expf(sc[mt][3] - m_new);
            psum += (p0 + p1) + (p2 + p3);
            uint2 pw_;
            pw_.x = (unsigned)f2b(p0) | ((unsigned)f2b(p1) << 16);
            pw_.y = (unsigned)f2b(p2) | ((unsigned)f2b(p3) << 16);
            *(uint2*)(Plw + mt * 16 + g * 4) = pw_;
        }
        psum += __shfl_xor(psum, 16);
        psum += __shfl_xor(psum, 32);
        l_run = l_run * alpha + psum;
        m_run = m_new;
        #pragma unroll
        for (int i = 0; i < 8; ++i) {
            oa[i][0] *= alpha; oa[i][1] *= alpha; oa[i][2] *= alpha; oa[i][3] *= alpha;
        }

        // ---- PV: O^T[d][q] += V^T-frag x P-frag (tok chunks kc=0,1) ----
        bf16x8 pf0 = *(const bf16x8*)(Plw + 8 * g);
        bf16x8 pf1 = *(const bf16x8*)(Plw + 32 + 8 * g);
        __builtin_amdgcn_s_setprio(1);
        #pragma unroll
        for (int dt = 0; dt < 8; ++dt) {
            const int vrow = dt * 16 + ln;
            const ushort_t* vrp = &Vls[cur][vrow * 64];
            bf16x8 vf0 = *(const bf16x8*)(vrp + ((g     ^ (vrow & 7)) * 8));
            bf16x8 vf1 = *(const bf16x8*)(vrp + (((g+4) ^ (vrow & 7)) * 8));
            oa[dt] = __builtin_amdgcn_mfma_f32_16x16x32_bf16(vf0, pf0, oa[dt], 0, 0, 0);
            oa[dt] = __builtin_amdgcn_mfma_f32_16x16x32_bf16(vf1, pf1, oa[dt], 0, 0, 0);
        }
        __builtin_amdgcn_s_setprio(0);
    }

    const float invl = 1.f / l_run;
    #pragma unroll
    for (int i = 0; i < 8; ++i) {
        oa[i][0] *= invl; oa[i][1] *= invl; oa[i][2] *= invl; oa[i][3] *= invl;
    }

    // ---- adapter: tokens 2048..2057 (+zeroed pad), separate softmax ----
    const ushort_t* karow = Kg + (size_t)(2048 + (ln < 10 ? ln : 9)) * DIM + hb;
    f32x4 sa4 = {};
    #pragma unroll
    for (int c = 0; c < 4; ++c) {
        bf16x8 kf = *(const bf16x8*)(karow + 8 * g + 32 * c);
        sa4 = __builtin_amdgcn_mfma_f32_16x16x32_bf16(kf, qf[c], sa4, 0, 0, 0);
    }
    float am = -3e38f;
    float pa[4];
    #pragma unroll
    for (int r = 0; r < 4; ++r) {
        int kl = g * 4 + r;
        pa[r] = (kl < 10) ? sa4[r] : -1e30f;
        am = fmaxf(am, pa[r]);
    }
    am = fmaxf(am, __shfl_xor(am, 16));
    am = fmaxf(am, __shfl_xor(am, 32));
    float asum = 0.f;
    #pragma unroll
    for (int r = 0; r < 4; ++r) { pa[r] = __expf(pa[r] - am); asum += pa[r]; }
    asum += __shfl_xor(asum, 16);
    asum += __shfl_xor(asum, 32);
    const float coef = ag / asum;
    {
        uint2 pw_;
        pw_.x = (unsigned)f2b(pa[0] * coef) | ((unsigned)f2b(pa[1] * coef) << 16);
        pw_.y = (unsigned)f2b(pa[2] * coef) | ((unsigned)f2b(pa[3] * coef) << 16);
        *(uint2*)(Plw + g * 4) = pw_;
        uint2 z2; z2.x = 0; z2.y = 0;
        *(uint2*)(Plw + 16 + g * 4) = z2;   // zero P[16..31]: MFMA reads k=0..31
    }
    bf16x8 paf = *(const bf16x8*)(Plw + 8 * g);
    #pragma unroll
    for (int dt = 0; dt < 8; ++dt) {
        const ushort_t* varow = Vt + (size_t)(hb + dt * 16 + ln) * VTP + 2048;
        bf16x8 vfa = *(const bf16x8*)(varow + 8 * g);
        oa[dt] = __builtin_amdgcn_mfma_f32_16x16x32_bf16(vfa, paf, oa[dt], 0, 0, 0);
    }

    ushort_t* outp = AO + (kvb + gq) * DIM + hb;
    #pragma unroll
    for (int dt = 0; dt < 8; ++dt) {
        ushort4 ov;
        ov.x = f2b(scrub(oa[dt][0], 1e8f));
        ov.y = f2b(scrub(oa[dt][1], 1e8f));
        ov.z = f2b(scrub(oa[dt][2], 1e8f));
        ov.w = f2b(scrub(oa[dt][3], 1e8f));
        *(ushort4*)(outp + dt * 16 + g * 4) = ov;
    }
}

// ---------------------------------------------------------------------------
// Legacy scalar flash attention (ws fallback path only).
// ---------------------------------------------------------------------------
__global__ __launch_bounds__(256) void attn_kernel(const ushort_t* __restrict__ Q,
                                                   const ushort_t* __restrict__ Kg,
                                                   const ushort_t* __restrict__ Vg,
                                                   const float* __restrict__ g1,
                                                   const float* __restrict__ g2,
                                                   const int* __restrict__ vsp,
                                                   ushort_t* __restrict__ AO)
{
    __shared__ float Qs[32 * 132];
    __shared__ float Ks[32 * 132];
    __shared__ float Vs[32 * 132];
    __shared__ float Ps[32 * 32];

    const int blk = blockIdx.x;
    const int q0  = (31 - (blk & 31)) * 32;
    const int h   = blk >> 5;
    const int t   = threadIdx.x;
    const int qi  = t >> 3;
    const int l8  = t & 7;
    const int vs  = *vsp;
    const int g_q = q0 + qi;
    const float scale = 0.08838834764831845f;
    const float g2h = g2[h];
    const float ag  = tanhf(g1[h]);

    #pragma unroll
    for (int p = 0; p < 4; ++p) {
        int idx = (p * 256 + t) * 4;
        int r = idx >> 7, d = idx & 127;
        ushort4 q4 = *(const ushort4*)(Q + (size_t)(q0 + r) * DIM + h * HD + d);
        *(float4*)(Qs + r * 132 + d) = make_float4(b2f(q4.x), b2f(q4.y), b2f(q4.z), b2f(q4.w));
    }

    float o[16];
    #pragma unroll
    for (int i = 0; i < 16; ++i) o[i] = 0.f;
    float m_run = -1e30f, l_run = 0.f;

    for (int k0 = 0; k0 <= q0 + 31; k0 += 32) {
        __syncthreads();
        #pragma unroll
        for (int p = 0; p < 4; ++p) {
            int idx = (p * 256 + t) * 4;
            int r = idx >> 7, d = idx & 127;
            size_t goff = (size_t)(k0 + r) * DIM + h * HD + d;
            ushort4 k4 = *(const ushort4*)(Kg + goff);
            ushort4 v4 = *(const ushort4*)(Vg + goff);
            *(float4*)(Ks + r * 132 + d) = make_float4(b2f(k4.x), b2f(k4.y), b2f(k4.z), b2f(k4.w));
            *(float4*)(Vs + r * 132 + d) = make_float4(b2f(v4.x), b2f(v4.y), b2f(v4.z), b2f(v4.w));
        }
        __syncthreads();

        float s[4];
        #pragma unroll
        for (int jj = 0; jj < 4; ++jj) s[jj] = 0.f;
        #pragma unroll 4
        for (int d = 0; d < 128; d += 4) {
            const float4 qv = *(const float4*)(Qs + qi * 132 + d);
            #pragma unroll
            for (int jj = 0; jj < 4; ++jj) {
                const float4 kv = *(const float4*)(Ks + (l8 + 8 * jj) * 132 + d);
                s[jj] += qv.x * kv.x + qv.y * kv.y + qv.z * kv.z + qv.w * kv.w;
            }
        }
        float mloc = -1e30f;
        #pragma unroll
        for (int jj = 0; jj < 4; ++jj) {
            int gk = k0 + l8 + 8 * jj;
            float sv = s[jj] * scale;
            if (gk > g_q) sv -= 1e9f;
            if (gk >= vs && gk < vs + MAXF && g_q >= vs + MAXF) sv += g2h;
            s[jj] = sv;
            mloc = fmaxf(mloc, sv);
        }
        mloc = fmaxf(mloc, __shfl_xor(mloc, 1));
        mloc = fmaxf(mloc, __shfl_xor(mloc, 2));
        mloc = fmaxf(mloc, __shfl_xor(mloc, 4));
        const float m_new = fmaxf(m_run, mloc);
        const float alpha = expf(m_run - m_new);
        float psum = 0.f;
        #pragma unroll
        for (int jj = 0; jj < 4; ++jj) {
            float pv = expf(s[jj] - m_new);
            psum += pv;
            Ps[qi * 32 + l8 + 8 * jj] = pv;
        }
        psum += __shfl_xor(psum, 1);
        psum += __shfl_xor(psum, 2);
        psum += __shfl_xor(psum, 4);
        l_run = l_run * alpha + psum;
        m_run = m_new;
        #pragma unroll
        for (int i = 0; i < 16; ++i) o[i] *= alpha;
        __syncthreads();

        #pragma unroll 4
        for (int kk = 0; kk < 32; ++kk) {
            const float pp = Ps[qi * 32 + kk];
            const float* vr = Vs + kk * 132 + l8 * 4;
            #pragma unroll
            for (int jj = 0; jj < 4; ++jj) {
                const float4 v4 = *(const float4*)(vr + jj * 32);
                o[jj*4+0] = fmaf(pp, v4.x, o[jj*4+0]);
                o[jj*4+1] = fmaf(pp, v4.y, o[jj*4+1]);
                o[jj*4+2] = fmaf(pp, v4.z, o[jj*4+2]);
                o[jj*4+3] = fmaf(pp, v4.w, o[jj*4+3]);
            }
        }
    }

    const float invl = 1.f / l_run;
    #pragma unroll
    for (int i = 0; i < 16; ++i) o[i] *= invl;

    __syncthreads();
    #pragma unroll
    for (int p = 0; p < 2; ++p) {
        int idx = p * 256 + t;
        if (idx < 320) {
            int fi = idx * 4; int r = fi >> 7; int d = fi & 127;
            size_t goff = (size_t)(SEQQ + r) * DIM + h * HD + d;
            ushort4 k4 = *(const ushort4*)(Kg + goff);
            ushort4 v4 = *(const ushort4*)(Vg + goff);
            *(float4*)(Ks + r * 132 + d) = make_float4(b2f(k4.x), b2f(k4.y), b2f(k4.z), b2f(k4.w));
            *(float4*)(Vs + r * 132 + d) = make_float4(b2f(v4.x), b2f(v4.y), b2f(v4.z), b2f(v4.w));
        }
    }
    __syncthreads();
    float sa[2] = {-1e30f, -1e30f};
    #pragma unroll
    for (int jj = 0; jj < 2; ++jj) {
        int kk = l8 + 8 * jj;
        if (kk < AL) {
            float acc = 0.f;
            #pragma unroll 4
            for (int d = 0; d < 128; d += 4) {
                const float4 qv = *(const float4*)(Qs + qi * 132 + d);
                const float4 kv = *(const float4*)(Ks + kk * 132 + d);
                acc += qv.x * kv.x + qv.y * kv.y + qv.z * kv.z + qv.w * kv.w;
            }
            sa[jj] = acc * scale;
        }
    }
    float am = fmaxf(sa[0], sa[1]);
    am = fmaxf(am, __shfl_xor(am, 1));
    am = fmaxf(am, __shfl_xor(am, 2));
    am = fmaxf(am, __shfl_xor(am, 4));
    float pa0 = expf(sa[0] - am);
    float pa1 = (l8 < 2) ? expf(sa[1] - am) : 0.f;
    float asum = pa0 + pa1;
    asum += __shfl_xor(asum, 1);
    asum += __shfl_xor(asum, 2);
    asum += __shfl_xor(asum, 4);
    const float coef = ag / asum;
    Ps[qi * 32 + l8] = pa0 * coef;
    if (l8 < 2) Ps[qi * 32 + 8 + l8] = pa1 * coef;
    __syncthreads();
    #pragma unroll
    for (int kk = 0; kk < AL; ++kk) {
        const float pp = Ps[qi * 32 + kk];
        const float* vr = Vs + kk * 132 + l8 * 4;
        #pragma unroll
        for (int jj = 0; jj < 4; ++jj) {
            const float4 v4 = *(const float4*)(vr + jj * 32);
            o[jj*4+0] = fmaf(pp, v4.x, o[jj*4+0]);
            o[jj*4+1] = fmaf(pp, v4.y, o[jj*4+1]);
            o[jj*4+2] = fmaf(pp, v4.z, o[jj*4+2]);
            o[jj*4+3] = fmaf(pp, v4.w, o[jj*4+3]);
        }
    }

    ushort_t* outp = AO + (size_t)g_q * DIM + h * HD + l8 * 4;
    #pragma unroll
    for (int jj = 0; jj < 4; ++jj) {
        ushort4 ov;
        ov.x = f2b(scrub(o[jj*4+0], 1e8f));
        ov.y = f2b(scrub(o[jj*4+1], 1e8f));
        ov.z = f2b(scrub(o[jj*4+2], 1e8f));
        ov.w = f2b(scrub(o[jj*4+3], 1e8f));
        *(ushort4*)(outp + jj * 32) = ov;
    }
}

// ---------------------------------------------------------------------------
extern "C" void kernel_launch(void* const* d_in, const int* in_sizes, int n_in,
                              void* d_out, int out_size, void* d_ws, size_t ws_size,
                              hipStream_t stream)
{
    const float* x   = (const float*)d_in[0];
    const float* adp = (const float*)d_in[1];
    /* d_in[2] mask: recomputed analytically */
    const float* fc  = (const float*)d_in[3];
    const float* fs  = (const float*)d_in[4];
    const float* wq  = (const float*)d_in[5];
    const float* wk  = (const float*)d_in[6];
    const float* wv  = (const float*)d_in[7];
    const float* wo  = (const float*)d_in[8];
    const float* g1  = (const float*)d_in[9];
    const float* g2  = (const float*)d_in[10];
    const int*   vsp = (const int*)d_in[11];

    float* out = (float*)d_out;

    const size_t rows2 = (size_t)BSZ * SEQQ;         // 2048
    const size_t qe2 = rows2 * DIM;                  // Qb (both batches)
    const size_t ke2 = (rows2 + AL) * DIM;           // Kb: 2058 rows token-major
    const size_t vte = (size_t)DIM * VTP;            // V^T [2048][2080]
    const size_t we  = (size_t)DIM * DIM;
    const size_t xe  = (size_t)BSZ * SEQQ * DIM;
    const size_t need = (qe2 + ke2 + vte + xe + 4 * we) * sizeof(ushort_t);  // ~67.3 MB

    if (ws_size >= need) {
        // ---- fast path ----
        // ws: Qb[2048](alias AO) | Kb[2058 rows] | VtG[2048][2080] | Xb | 4 weights
        ushort_t* Qb  = (ushort_t*)d_ws;
        ushort_t* Kb  = Qb + qe2;
        ushort_t* VtG = Kb + ke2;
        ushort_t* Xb  = VtG + vte;
        ushort_t* Wqb = Xb + xe;
        ushort_t* Wkb = Wqb + we;
        ushort_t* Wvb = Wkb + we;
        ushort_t* Wob = Wvb + we;

        cvt5<<<dim3(2048, 5), 256, 0, stream>>>(wq, wk, wv, wo, x,
                                                Wqb, Wkb, Wvb, Wob, Xb);

        // adapter K rows 2048..2057 (token-major) + V^T cols 2048..2057 (+pad)
        adapter_gemm<<<512, 256, 0, stream>>>(adp, Wkb, Wvb,
                                              Kb + rows2 * DIM, VtG,
                                              100.0f);

        // fused QKV for both batches (M=2048); z=0/1 rope fused, z=2 V^T.
        // r11 config (BK=32) -- best measured total.
        gemm_bt<0><<<dim3(16, 16, 3), 256, 0, stream>>>(
            Xb, Wqb, Wkb, Wvb, Qb, Kb, VtG,
            fc, fs, 0.08838834764831845f, 1e5f);

        // MFMA flash attention, both batches, one launch (CU-pair balanced).
        attn_mfma<<<512, 256, 0, stream>>>(Qb, Kb, VtG, g1, g2, vsp, Qb /* AO alias */);

        // final projection -> fp32 d_out. r13: BK=64 + XOR swizzle (WO's LDS
        // conflicts sit on the critical path at 1-2 blocks/CU). canary 1e12.
        gemm_wo<<<dim3(32, 16), 256, 0, stream>>>(Qb, Wob, out, 1e12f);
    } else {
        // ---- fallback: round-1 verified per-batch path ----
        const size_t qe = (size_t)SEQQ * DIM;
        const size_t ke = (size_t)KVROWS * DIM;
        ushort_t* Qb = (ushort_t*)d_ws;
        ushort_t* Kb = Qb + qe;
        ushort_t* Vb = Kb + ke;

        mfma_gemm<true, false><<<dim3(16, 1, 2), 256, 0, stream>>>(
            adp, wk, wv, wv,
            Kb + qe, Vb + qe, Vb,
            AL, 100.0f);

        for (int b = 0; b < BSZ; ++b) {
            const long xo = (long)b * SEQQ * DIM;
            mfma_gemm<true, false><<<dim3(16, 8, 3), 256, 0, stream>>>(
                x + xo, wq, wk, wv, Qb, Kb, Vb, SEQQ, 1e5f);

            rope_kernel<<<dim3(4096, 2), 256, 0, stream>>>(Qb, Kb, fc, fs, 1.0f);

            attn_kernel<<<NH * (SEQQ / 32), 256, 0, stream>>>(Qb, Kb, Vb, g1, g2, vsp, Qb);

            mfma_gemm<false, true><<<dim3(16, 8, 1), 256, 0, stream>>>(
                Qb, wo, wo, wo, out + xo, out + xo, out + xo, SEQQ, 1e12f);
        }
    }
}